// Round 13
// baseline (695.730 us; speedup 1.0000x reference)
//
#include <hip/hip_runtime.h>
#include <hip/hip_bf16.h>

#define N_NODES 100000
#define N_EDGES 1600000
#define N_SUB   2000
#define N_GRAPH 64
#define HID     64
#define NLAYERS 3
#define SCAN_B  1024
#define N_SCANB ((N_NODES + SCAN_B - 1) / SCAN_B)   // 98

__device__ __forceinline__ float bcastf(float v, int l) {
  return __int_as_float(__builtin_amdgcn_readlane(__float_as_int(v), l));
}

// ============ CSR build (round-5 proven shape) =============================
__global__ __launch_bounds__(256) void count_slot_kernel(
    const int4* __restrict__ dst4, int* __restrict__ deg,
    int4* __restrict__ slot4) {
  int t = blockIdx.x * blockDim.x + threadIdx.x;
  int nt = gridDim.x * blockDim.x;
  for (int e4 = t; e4 < N_EDGES / 4; e4 += nt) {
    int4 d = dst4[e4];
    int4 p;
    p.x = atomicAdd(&deg[d.x], 1);
    p.y = atomicAdd(&deg[d.y], 1);
    p.z = atomicAdd(&deg[d.z], 1);
    p.w = atomicAdd(&deg[d.w], 1);
    slot4[e4] = p;
  }
}

__global__ __launch_bounds__(SCAN_B) void scan_block_kernel(
    const int* __restrict__ deg, int* __restrict__ rowptr,
    int* __restrict__ partials) {
  __shared__ int sm[SCAN_B];
  const int tid = threadIdx.x;
  const int g = blockIdx.x * SCAN_B + tid;
  int v = (g < N_NODES) ? deg[g] : 0;
  sm[tid] = v;
  __syncthreads();
  for (int off = 1; off < SCAN_B; off <<= 1) {
    int t = (tid >= off) ? sm[tid - off] : 0;
    __syncthreads();
    sm[tid] += t;
    __syncthreads();
  }
  if (g < N_NODES) rowptr[g] = sm[tid] - v;
  if (tid == SCAN_B - 1) partials[blockIdx.x] = sm[tid];
}

__global__ __launch_bounds__(128) void scan_partials_kernel(int* partials) {
  __shared__ int sm[128];
  const int tid = threadIdx.x;
  int v = (tid < N_SCANB) ? partials[tid] : 0;
  sm[tid] = v;
  __syncthreads();
  for (int off = 1; off < 128; off <<= 1) {
    int t = (tid >= off) ? sm[tid - off] : 0;
    __syncthreads();
    sm[tid] += t;
    __syncthreads();
  }
  if (tid < N_SCANB) partials[tid] = sm[tid] - v;
}

__global__ __launch_bounds__(SCAN_B) void add_offsets_kernel(
    int* __restrict__ rowptr, const int* __restrict__ partials) {
  const int g = blockIdx.x * SCAN_B + threadIdx.x;
  if (g < N_NODES) rowptr[g] += partials[blockIdx.x];
  if (g == 0) rowptr[N_NODES] = N_EDGES;
}

__global__ __launch_bounds__(256) void fill_csr2_kernel(
    const int4* __restrict__ src4, const int4* __restrict__ dst4,
    const int4* __restrict__ slot4, const int* __restrict__ rowptr,
    int* __restrict__ csr) {
  int t = blockIdx.x * blockDim.x + threadIdx.x;
  int nt = gridDim.x * blockDim.x;
  for (int e4 = t; e4 < N_EDGES / 4; e4 += nt) {
    int4 s = src4[e4];
    int4 d = dst4[e4];
    int4 p = slot4[e4];
    csr[rowptr[d.x] + p.x] = s.x;
    csr[rowptr[d.y] + p.y] = s.y;
    csr[rowptr[d.z] + p.z] = s.z;
    csr[rowptr[d.w] + p.w] = s.w;
  }
}

// ============ conv1: scalar gather + tiny MLP (proven) =====================
__global__ __launch_bounds__(256) void conv1_agg_kernel(
    const float* __restrict__ x, const int* __restrict__ rowptr,
    const int* __restrict__ csr, float* __restrict__ agg1) {
  int t = blockIdx.x * blockDim.x + threadIdx.x;
  int nt = gridDim.x * blockDim.x;
  for (int i = t; i < N_NODES; i += nt) {
    float a = x[i];
    int end = rowptr[i + 1];
    for (int e = rowptr[i]; e < end; e++) a += x[csr[e]];
    agg1[i] = a;
  }
}

__global__ __launch_bounds__(256) void conv1_mlp(
    const float* __restrict__ agg1,
    const float* __restrict__ w1, const float* __restrict__ b1,
    const float* __restrict__ w2, const float* __restrict__ b2,
    float* __restrict__ h) {
  const int lane = threadIdx.x & 63;
  const int wid = (blockIdx.x * blockDim.x + threadIdx.x) >> 6;
  const int nw = (gridDim.x * blockDim.x) >> 6;
  const float w1l = w1[lane], b1l = b1[lane], b2l = b2[lane];
  float w2c[64];
#pragma unroll
  for (int k = 0; k < 64; k++) w2c[k] = w2[k * 64 + lane];

  for (int i = wid; i < N_NODES; i += nw) {
    float hv = agg1[i];
    float y1 = fmaxf(hv * w1l + b1l, 0.f);
    float a0 = b2l, a1 = 0.f, a2 = 0.f, a3 = 0.f;
#pragma unroll
    for (int k = 0; k < 64; k += 4) {
      a0 += bcastf(y1, k)     * w2c[k];
      a1 += bcastf(y1, k + 1) * w2c[k + 1];
      a2 += bcastf(y1, k + 2) * w2c[k + 2];
      a3 += bcastf(y1, k + 3) * w2c[k + 3];
    }
    h[i * 64 + lane] = fmaxf(a0 + a1 + a2 + a3, 0.f);
  }
}

// ============ FUSED gather + GIN MLP (+ optional pool) =====================
// Wave-per-node. Gather phase: lane=(q,su) reads float4s of neighbor rows
// (4-deep ILP); butterfly reduce leaves ALL lanes holding the channel-group
// totals (channels 4*su .. 4*su+3). MLP phase: L1 via readlane broadcast of
// the in-register agg row (lane j<16 owns channels 4j..4j+3), L2 via the
// proven y1 broadcast. No agg round-trip (saves 51.2 MB/layer).
template <bool POOL>
__global__ __launch_bounds__(256) void gin_layer_fused(
    const float4* __restrict__ h4, const int* __restrict__ rowptr,
    const int* __restrict__ csr,
    const float* __restrict__ w1, const float* __restrict__ b1,
    const float* __restrict__ w2, const float* __restrict__ b2,
    const int* __restrict__ n2s,
    float* __restrict__ hout, float* __restrict__ subp) {
  const int lane = threadIdx.x & 63;
  const int q = lane >> 4;
  const int su = lane & 15;
  const int wid = (blockIdx.x * blockDim.x + threadIdx.x) >> 6;
  const int nw = (gridDim.x * blockDim.x) >> 6;
  const float b1l = b1[lane], b2l = b2[lane];
  float w1c[64], w2c[64];
#pragma unroll
  for (int k = 0; k < 64; k++) {
    w1c[k] = w1[k * 64 + lane];
    w2c[k] = w2[k * 64 + lane];
  }

  for (int i = wid; i < N_NODES; i += nw) {
    // ---- gather neighbors ----
    const int beg = rowptr[i], end = rowptr[i + 1];
    float ax = 0.f, ay = 0.f, az = 0.f, aw = 0.f;
    for (int c = beg; c < end; c += 64) {
      const int nb = min(64, end - c);
      int idx = csr[c + min(lane, nb - 1)];
      int j = 0;
      for (; j + 16 <= nb; j += 16) {
        int s0 = __shfl(idx, j + q, 64);
        int s1 = __shfl(idx, j + 4 + q, 64);
        int s2 = __shfl(idx, j + 8 + q, 64);
        int s3 = __shfl(idx, j + 12 + q, 64);
        float4 v0 = h4[(size_t)s0 * 16 + su];
        float4 v1 = h4[(size_t)s1 * 16 + su];
        float4 v2 = h4[(size_t)s2 * 16 + su];
        float4 v3 = h4[(size_t)s3 * 16 + su];
        ax += (v0.x + v1.x) + (v2.x + v3.x);
        ay += (v0.y + v1.y) + (v2.y + v3.y);
        az += (v0.z + v1.z) + (v2.z + v3.z);
        aw += (v0.w + v1.w) + (v2.w + v3.w);
      }
      for (; j < nb; j += 4) {
        int li = j + q;
        int s = __shfl(idx, li < nb ? li : 0, 64);
        float4 v = h4[(size_t)s * 16 + su];
        if (li < nb) { ax += v.x; ay += v.y; az += v.z; aw += v.w; }
      }
    }
    // butterfly: afterwards ALL lanes hold the cross-quarter totals
    ax += __shfl_xor(ax, 16, 64); ay += __shfl_xor(ay, 16, 64);
    az += __shfl_xor(az, 16, 64); aw += __shfl_xor(aw, 16, 64);
    ax += __shfl_xor(ax, 32, 64); ay += __shfl_xor(ay, 32, 64);
    az += __shfl_xor(az, 32, 64); aw += __shfl_xor(aw, 32, 64);
    // self term (16 unique float4s, broadcast within wave)
    float4 self = h4[(size_t)i * 16 + su];
    const float a0 = ax + self.x, a1 = ay + self.y;
    const float a2 = az + self.z, a3 = aw + self.w;

    // ---- MLP layer 1: lane = output channel; input row lives in regs,
    //      channel 4j+e is in lane j's a_e (j = 0..15) ----
    float c0 = b1l, c1 = 0.f, c2 = 0.f, c3 = 0.f;
#pragma unroll
    for (int j = 0; j < 16; j++) {
      c0 = fmaf(bcastf(a0, j), w1c[4 * j],     c0);
      c1 = fmaf(bcastf(a1, j), w1c[4 * j + 1], c1);
      c2 = fmaf(bcastf(a2, j), w1c[4 * j + 2], c2);
      c3 = fmaf(bcastf(a3, j), w1c[4 * j + 3], c3);
    }
    float y1 = fmaxf(c0 + c1 + c2 + c3, 0.f);

    // ---- MLP layer 2 ----
    c0 = b2l; c1 = 0.f; c2 = 0.f; c3 = 0.f;
#pragma unroll
    for (int k = 0; k < 64; k += 4) {
      c0 = fmaf(bcastf(y1, k),     w2c[k],     c0);
      c1 = fmaf(bcastf(y1, k + 1), w2c[k + 1], c1);
      c2 = fmaf(bcastf(y1, k + 2), w2c[k + 2], c2);
      c3 = fmaf(bcastf(y1, k + 3), w2c[k + 3], c3);
    }
    float y2 = fmaxf(c0 + c1 + c2 + c3, 0.f);

    if (POOL) {
      atomicAdd(&subp[(size_t)n2s[i] * 64 + lane], y2);
    } else {
      hout[(size_t)i * 64 + lane] = y2;
    }
  }
}

// ============ subgraph -> graph pooling + head =============================
__global__ __launch_bounds__(256) void pool_sub(
    const float* __restrict__ sub, const int* __restrict__ s2g,
    float* __restrict__ gp) {
  const int lane = threadIdx.x & 63;
  const int wid = (blockIdx.x * blockDim.x + threadIdx.x) >> 6;
  const int nw = (gridDim.x * blockDim.x) >> 6;
  for (int s = wid; s < N_SUB; s += nw) {
    int g = s2g[s];
    atomicAdd(&gp[g * 64 + lane], sub[s * 64 + lane]);
  }
}

__global__ __launch_bounds__(64) void head_kernel(
    const float* __restrict__ gp,
    const float* __restrict__ w1, const float* __restrict__ b1,
    const float* __restrict__ w2, const float* __restrict__ b2,
    float* __restrict__ out) {
  const int g = blockIdx.x;
  const int lane = threadIdx.x;
  float v = gp[g * 64 + lane];
  float acc = b1[lane];
#pragma unroll
  for (int k = 0; k < 64; k++) acc += bcastf(v, k) * w1[k * 64 + lane];
  float y1 = fmaxf(acc, 0.f);
  const int o = lane & 7;
  float acc2 = b2[o];
#pragma unroll
  for (int k = 0; k < 64; k++) acc2 += bcastf(y1, k) * w2[k * 8 + o];
  float m = -1e30f;
#pragma unroll
  for (int oo = 0; oo < 8; oo++) m = fmaxf(m, bcastf(acc2, oo));
  float s = 0.f;
#pragma unroll
  for (int oo = 0; oo < 8; oo++) s += expf(bcastf(acc2, oo) - m);
  float ls = logf(s);
  if (lane < 8) out[g * 8 + lane] = acc2 - m - ls;
}

// ===========================================================================
extern "C" void kernel_launch(void* const* d_in, const int* in_sizes, int n_in,
                              void* d_out, int out_size, void* d_ws,
                              size_t ws_size, hipStream_t stream) {
  const float* x   = (const float*)d_in[0];
  const int* ei    = (const int*)d_in[1];
  const int* src   = ei;
  const int* dst   = ei + N_EDGES;
  const int* n2s   = (const int*)d_in[2];
  const int* s2g   = (const int*)d_in[3];
  const float* c1w1 = (const float*)d_in[4];
  const float* c1b1 = (const float*)d_in[5];
  const float* c1w2 = (const float*)d_in[6];
  const float* c1b2 = (const float*)d_in[7];
  const float* cw1  = (const float*)d_in[8];
  const float* cb1  = (const float*)d_in[9];
  const float* cw2  = (const float*)d_in[10];
  const float* cb2  = (const float*)d_in[11];
  const float* l1w  = (const float*)d_in[12];
  const float* l1b  = (const float*)d_in[13];
  const float* l2w  = (const float*)d_in[14];
  const float* l2b  = (const float*)d_in[15];

  // workspace layout (all 4-byte elements)
  char* p = (char*)d_ws;
  float* h      = (float*)p;  p += (size_t)N_NODES * 64 * 4;   // 25.6 MB
  float* h2     = (float*)p;  p += (size_t)N_NODES * 64 * 4;   // 25.6 MB
  int*   csr    = (int*)p;    p += (size_t)N_EDGES * 4;        // 6.4 MB
  int*   rowptr = (int*)p;    p += (size_t)(N_NODES + 1) * 4;
  int*   deg    = (int*)p;    p += (size_t)N_NODES * 4;
  int*   part   = (int*)p;    p += 256 * 4;
  float* agg1   = (float*)p;  p += (size_t)N_NODES * 4;
  float* sub    = (float*)p;  p += (size_t)N_SUB * 64 * 4;
  float* gp     = (float*)p;  p += (size_t)N_GRAPH * 64 * 4;
  if ((size_t)(p - (char*)d_ws) > ws_size) return;  // fail loudly

  // slot (6.4 MB) aliases h2: h2 is first written by layer-0's fused kernel,
  // which runs after the CSR build completes.
  int* slot = (int*)h2;

  float* outf = (float*)d_out;

  // ---- build CSR (group edges by dst) once; reused by all 4 aggregations
  hipMemsetAsync(deg, 0, N_NODES * sizeof(int), stream);
  count_slot_kernel<<<2048, 256, 0, stream>>>(
      (const int4*)dst, deg, (int4*)slot);
  scan_block_kernel<<<N_SCANB, SCAN_B, 0, stream>>>(deg, rowptr, part);
  scan_partials_kernel<<<1, 128, 0, stream>>>(part);
  add_offsets_kernel<<<N_SCANB, SCAN_B, 0, stream>>>(rowptr, part);
  fill_csr2_kernel<<<2048, 256, 0, stream>>>(
      (const int4*)src, (const int4*)dst, (const int4*)slot, rowptr, csr);

  // ---- conv1
  conv1_agg_kernel<<<1024, 256, 0, stream>>>(x, rowptr, csr, agg1);
  conv1_mlp<<<2048, 256, 0, stream>>>(agg1, c1w1, c1b1, c1w2, c1b2, h);

  // zero pooling buffers before the fused last layer
  hipMemsetAsync(sub, 0, N_SUB * 64 * sizeof(float), stream);
  hipMemsetAsync(gp, 0, N_GRAPH * 64 * sizeof(float), stream);

  // ---- 3 fused GIN layers (gather+MLP; h ping-pongs h -> h2 -> h; last
  //      layer pools directly into sub)
  gin_layer_fused<false><<<2048, 256, 0, stream>>>(
      (const float4*)h, rowptr, csr, cw1 + 0 * 4096, cb1 + 0 * 64,
      cw2 + 0 * 4096, cb2 + 0 * 64, n2s, h2, nullptr);
  gin_layer_fused<false><<<2048, 256, 0, stream>>>(
      (const float4*)h2, rowptr, csr, cw1 + 1 * 4096, cb1 + 1 * 64,
      cw2 + 1 * 4096, cb2 + 1 * 64, n2s, h, nullptr);
  gin_layer_fused<true><<<2048, 256, 0, stream>>>(
      (const float4*)h, rowptr, csr, cw1 + 2 * 4096, cb1 + 2 * 64,
      cw2 + 2 * 4096, cb2 + 2 * 64, n2s, nullptr, sub);

  // ---- subgraph -> graph pool + head
  pool_sub<<<64, 256, 0, stream>>>(sub, s2g, gp);
  head_kernel<<<N_GRAPH, 64, 0, stream>>>(gp, l1w, l1b, l2w, l2b, outf);
}

// Round 16
// 582.977 us; speedup vs baseline: 1.1934x; 1.1934x over previous
//
#include <hip/hip_runtime.h>
#include <hip/hip_bf16.h>

#define N_NODES 100000
#define N_EDGES 1600000
#define N_SUB   2000
#define N_GRAPH 64
#define HID     64
#define NLAYERS 3
#define SCAN_B  1024
#define N_SCANB ((N_NODES + SCAN_B - 1) / SCAN_B)   // 98

__device__ __forceinline__ float bcastf(float v, int l) {
  return __int_as_float(__builtin_amdgcn_readlane(__float_as_int(v), l));
}

// ============ CSR build (round-5 proven shape) =============================
__global__ __launch_bounds__(256) void count_slot_kernel(
    const int4* __restrict__ dst4, int* __restrict__ deg,
    int4* __restrict__ slot4) {
  int t = blockIdx.x * blockDim.x + threadIdx.x;
  int nt = gridDim.x * blockDim.x;
  for (int e4 = t; e4 < N_EDGES / 4; e4 += nt) {
    int4 d = dst4[e4];
    int4 p;
    p.x = atomicAdd(&deg[d.x], 1);
    p.y = atomicAdd(&deg[d.y], 1);
    p.z = atomicAdd(&deg[d.z], 1);
    p.w = atomicAdd(&deg[d.w], 1);
    slot4[e4] = p;
  }
}

__global__ __launch_bounds__(SCAN_B) void scan_block_kernel(
    const int* __restrict__ deg, int* __restrict__ rowptr,
    int* __restrict__ partials) {
  __shared__ int sm[SCAN_B];
  const int tid = threadIdx.x;
  const int g = blockIdx.x * SCAN_B + tid;
  int v = (g < N_NODES) ? deg[g] : 0;
  sm[tid] = v;
  __syncthreads();
  for (int off = 1; off < SCAN_B; off <<= 1) {
    int t = (tid >= off) ? sm[tid - off] : 0;
    __syncthreads();
    sm[tid] += t;
    __syncthreads();
  }
  if (g < N_NODES) rowptr[g] = sm[tid] - v;
  if (tid == SCAN_B - 1) partials[blockIdx.x] = sm[tid];
}

__global__ __launch_bounds__(128) void scan_partials_kernel(int* partials) {
  __shared__ int sm[128];
  const int tid = threadIdx.x;
  int v = (tid < N_SCANB) ? partials[tid] : 0;
  sm[tid] = v;
  __syncthreads();
  for (int off = 1; off < 128; off <<= 1) {
    int t = (tid >= off) ? sm[tid - off] : 0;
    __syncthreads();
    sm[tid] += t;
    __syncthreads();
  }
  if (tid < N_SCANB) partials[tid] = sm[tid] - v;
}

__global__ __launch_bounds__(SCAN_B) void add_offsets_kernel(
    int* __restrict__ rowptr, const int* __restrict__ partials) {
  const int g = blockIdx.x * SCAN_B + threadIdx.x;
  if (g < N_NODES) rowptr[g] += partials[blockIdx.x];
  if (g == 0) rowptr[N_NODES] = N_EDGES;
}

__global__ __launch_bounds__(256) void fill_csr2_kernel(
    const int4* __restrict__ src4, const int4* __restrict__ dst4,
    const int4* __restrict__ slot4, const int* __restrict__ rowptr,
    int* __restrict__ csr) {
  int t = blockIdx.x * blockDim.x + threadIdx.x;
  int nt = gridDim.x * blockDim.x;
  for (int e4 = t; e4 < N_EDGES / 4; e4 += nt) {
    int4 s = src4[e4];
    int4 d = dst4[e4];
    int4 p = slot4[e4];
    csr[rowptr[d.x] + p.x] = s.x;
    csr[rowptr[d.y] + p.y] = s.y;
    csr[rowptr[d.z] + p.z] = s.z;
    csr[rowptr[d.w] + p.w] = s.w;
  }
}

// ============ conv1: scalar gather + tiny MLP (proven) =====================
__global__ __launch_bounds__(256) void conv1_agg_kernel(
    const float* __restrict__ x, const int* __restrict__ rowptr,
    const int* __restrict__ csr, float* __restrict__ agg1) {
  int t = blockIdx.x * blockDim.x + threadIdx.x;
  int nt = gridDim.x * blockDim.x;
  for (int i = t; i < N_NODES; i += nt) {
    float a = x[i];
    int end = rowptr[i + 1];
    for (int e = rowptr[i]; e < end; e++) a += x[csr[e]];
    agg1[i] = a;
  }
}

__global__ __launch_bounds__(256) void conv1_mlp(
    const float* __restrict__ agg1,
    const float* __restrict__ w1, const float* __restrict__ b1,
    const float* __restrict__ w2, const float* __restrict__ b2,
    float* __restrict__ h) {
  const int lane = threadIdx.x & 63;
  const int wid = (blockIdx.x * blockDim.x + threadIdx.x) >> 6;
  const int nw = (gridDim.x * blockDim.x) >> 6;
  const float w1l = w1[lane], b1l = b1[lane], b2l = b2[lane];
  float w2c[64];
#pragma unroll
  for (int k = 0; k < 64; k++) w2c[k] = w2[k * 64 + lane];

  for (int i = wid; i < N_NODES; i += nw) {
    float hv = agg1[i];
    float y1 = fmaxf(hv * w1l + b1l, 0.f);
    float a0 = b2l, a1 = 0.f, a2 = 0.f, a3 = 0.f;
#pragma unroll
    for (int k = 0; k < 64; k += 4) {
      a0 += bcastf(y1, k)     * w2c[k];
      a1 += bcastf(y1, k + 1) * w2c[k + 1];
      a2 += bcastf(y1, k + 2) * w2c[k + 2];
      a3 += bcastf(y1, k + 3) * w2c[k + 3];
    }
    h[i * 64 + lane] = fmaxf(a0 + a1 + a2 + a3, 0.f);
  }
}

// ============ 64-channel gather (proven, standalone = high occupancy) ======
__global__ __launch_bounds__(256) void gather64_f4_kernel(
    const float4* __restrict__ h4, const int* __restrict__ rowptr,
    const int* __restrict__ csr, float4* __restrict__ agg4) {
  const int lane = threadIdx.x & 63;
  const int q = lane >> 4;
  const int sub = lane & 15;
  const int wid = (blockIdx.x * blockDim.x + threadIdx.x) >> 6;
  const int nw = (gridDim.x * blockDim.x) >> 6;
  for (int i = wid; i < N_NODES; i += nw) {
    const int beg = rowptr[i], end = rowptr[i + 1];
    float ax = 0.f, ay = 0.f, az = 0.f, aw = 0.f;
    for (int c = beg; c < end; c += 64) {
      const int nb = min(64, end - c);
      int idx = csr[c + min(lane, nb - 1)];
      int j = 0;
      for (; j + 16 <= nb; j += 16) {
        int s0 = __shfl(idx, j + q, 64);
        int s1 = __shfl(idx, j + 4 + q, 64);
        int s2 = __shfl(idx, j + 8 + q, 64);
        int s3 = __shfl(idx, j + 12 + q, 64);
        float4 v0 = h4[(size_t)s0 * 16 + sub];
        float4 v1 = h4[(size_t)s1 * 16 + sub];
        float4 v2 = h4[(size_t)s2 * 16 + sub];
        float4 v3 = h4[(size_t)s3 * 16 + sub];
        ax += (v0.x + v1.x) + (v2.x + v3.x);
        ay += (v0.y + v1.y) + (v2.y + v3.y);
        az += (v0.z + v1.z) + (v2.z + v3.z);
        aw += (v0.w + v1.w) + (v2.w + v3.w);
      }
      for (; j < nb; j += 4) {
        int li = j + q;
        int s = __shfl(idx, li < nb ? li : 0, 64);
        float4 v = h4[(size_t)s * 16 + sub];
        if (li < nb) { ax += v.x; ay += v.y; az += v.z; aw += v.w; }
      }
    }
    ax += __shfl_xor(ax, 16, 64); ay += __shfl_xor(ay, 16, 64);
    az += __shfl_xor(az, 16, 64); aw += __shfl_xor(aw, 16, 64);
    ax += __shfl_xor(ax, 32, 64); ay += __shfl_xor(ay, 32, 64);
    az += __shfl_xor(az, 32, 64); aw += __shfl_xor(aw, 32, 64);
    if (q == 0) {
      float4 self = h4[(size_t)i * 16 + sub];
      float4 r;
      r.x = ax + self.x; r.y = ay + self.y;
      r.z = az + self.z; r.w = aw + self.w;
      agg4[(size_t)i * 16 + sub] = r;
    }
  }
}

// ============ GIN MLP (round-8 proven readlane form) =======================
__global__ __launch_bounds__(256) void gin_mlp(
    const float* __restrict__ agg,
    const float* __restrict__ w1, const float* __restrict__ b1,
    const float* __restrict__ w2, const float* __restrict__ b2,
    float* __restrict__ h) {
  const int lane = threadIdx.x & 63;
  const int wid = (blockIdx.x * blockDim.x + threadIdx.x) >> 6;
  const int nw = (gridDim.x * blockDim.x) >> 6;
  const float b1l = b1[lane], b2l = b2[lane];
  float w1c[64], w2c[64];
#pragma unroll
  for (int k = 0; k < 64; k++) {
    w1c[k] = w1[k * 64 + lane];
    w2c[k] = w2[k * 64 + lane];
  }

  for (int i = wid; i < N_NODES; i += nw) {
    float in = agg[i * 64 + lane];
    float a0 = b1l, a1 = 0.f, a2 = 0.f, a3 = 0.f;
#pragma unroll
    for (int k = 0; k < 64; k += 4) {
      a0 += bcastf(in, k)     * w1c[k];
      a1 += bcastf(in, k + 1) * w1c[k + 1];
      a2 += bcastf(in, k + 2) * w1c[k + 2];
      a3 += bcastf(in, k + 3) * w1c[k + 3];
    }
    float y1 = fmaxf(a0 + a1 + a2 + a3, 0.f);
    a0 = b2l; a1 = 0.f; a2 = 0.f; a3 = 0.f;
#pragma unroll
    for (int k = 0; k < 64; k += 4) {
      a0 += bcastf(y1, k)     * w2c[k];
      a1 += bcastf(y1, k + 1) * w2c[k + 1];
      a2 += bcastf(y1, k + 2) * w2c[k + 2];
      a3 += bcastf(y1, k + 3) * w2c[k + 3];
    }
    h[i * 64 + lane] = fmaxf(a0 + a1 + a2 + a3, 0.f);
  }
}

// Last GIN layer fused with node->subgraph pooling (round-8 proven: the
// coalesced row atomic costs ~nothing and saves the pool_nodes pass).
__global__ __launch_bounds__(256) void gin_mlp_pool(
    const float* __restrict__ agg,
    const float* __restrict__ w1, const float* __restrict__ b1,
    const float* __restrict__ w2, const float* __restrict__ b2,
    const int* __restrict__ n2s, float* __restrict__ sub) {
  const int lane = threadIdx.x & 63;
  const int wid = (blockIdx.x * blockDim.x + threadIdx.x) >> 6;
  const int nw = (gridDim.x * blockDim.x) >> 6;
  const float b1l = b1[lane], b2l = b2[lane];
  float w1c[64], w2c[64];
#pragma unroll
  for (int k = 0; k < 64; k++) {
    w1c[k] = w1[k * 64 + lane];
    w2c[k] = w2[k * 64 + lane];
  }

  for (int i = wid; i < N_NODES; i += nw) {
    float in = agg[i * 64 + lane];
    float a0 = b1l, a1 = 0.f, a2 = 0.f, a3 = 0.f;
#pragma unroll
    for (int k = 0; k < 64; k += 4) {
      a0 += bcastf(in, k)     * w1c[k];
      a1 += bcastf(in, k + 1) * w1c[k + 1];
      a2 += bcastf(in, k + 2) * w1c[k + 2];
      a3 += bcastf(in, k + 3) * w1c[k + 3];
    }
    float y1 = fmaxf(a0 + a1 + a2 + a3, 0.f);
    a0 = b2l; a1 = 0.f; a2 = 0.f; a3 = 0.f;
#pragma unroll
    for (int k = 0; k < 64; k += 4) {
      a0 += bcastf(y1, k)     * w2c[k];
      a1 += bcastf(y1, k + 1) * w2c[k + 1];
      a2 += bcastf(y1, k + 2) * w2c[k + 2];
      a3 += bcastf(y1, k + 3) * w2c[k + 3];
    }
    float y2 = fmaxf(a0 + a1 + a2 + a3, 0.f);
    atomicAdd(&sub[(size_t)n2s[i] * 64 + lane], y2);
  }
}

// ============ subgraph -> graph pooling + head =============================
__global__ __launch_bounds__(256) void pool_sub(
    const float* __restrict__ sub, const int* __restrict__ s2g,
    float* __restrict__ gp) {
  const int lane = threadIdx.x & 63;
  const int wid = (blockIdx.x * blockDim.x + threadIdx.x) >> 6;
  const int nw = (gridDim.x * blockDim.x) >> 6;
  for (int s = wid; s < N_SUB; s += nw) {
    int g = s2g[s];
    atomicAdd(&gp[g * 64 + lane], sub[s * 64 + lane]);
  }
}

__global__ __launch_bounds__(64) void head_kernel(
    const float* __restrict__ gp,
    const float* __restrict__ w1, const float* __restrict__ b1,
    const float* __restrict__ w2, const float* __restrict__ b2,
    float* __restrict__ out) {
  const int g = blockIdx.x;
  const int lane = threadIdx.x;
  float v = gp[g * 64 + lane];
  float acc = b1[lane];
#pragma unroll
  for (int k = 0; k < 64; k++) acc += bcastf(v, k) * w1[k * 64 + lane];
  float y1 = fmaxf(acc, 0.f);
  const int o = lane & 7;
  float acc2 = b2[o];
#pragma unroll
  for (int k = 0; k < 64; k++) acc2 += bcastf(y1, k) * w2[k * 8 + o];
  float m = -1e30f;
#pragma unroll
  for (int oo = 0; oo < 8; oo++) m = fmaxf(m, bcastf(acc2, oo));
  float s = 0.f;
#pragma unroll
  for (int oo = 0; oo < 8; oo++) s += expf(bcastf(acc2, oo) - m);
  float ls = logf(s);
  if (lane < 8) out[g * 8 + lane] = acc2 - m - ls;
}

// ===========================================================================
extern "C" void kernel_launch(void* const* d_in, const int* in_sizes, int n_in,
                              void* d_out, int out_size, void* d_ws,
                              size_t ws_size, hipStream_t stream) {
  const float* x   = (const float*)d_in[0];
  const int* ei    = (const int*)d_in[1];
  const int* src   = ei;
  const int* dst   = ei + N_EDGES;
  const int* n2s   = (const int*)d_in[2];
  const int* s2g   = (const int*)d_in[3];
  const float* c1w1 = (const float*)d_in[4];
  const float* c1b1 = (const float*)d_in[5];
  const float* c1w2 = (const float*)d_in[6];
  const float* c1b2 = (const float*)d_in[7];
  const float* cw1  = (const float*)d_in[8];
  const float* cb1  = (const float*)d_in[9];
  const float* cw2  = (const float*)d_in[10];
  const float* cb2  = (const float*)d_in[11];
  const float* l1w  = (const float*)d_in[12];
  const float* l1b  = (const float*)d_in[13];
  const float* l2w  = (const float*)d_in[14];
  const float* l2b  = (const float*)d_in[15];

  // workspace layout (all 4-byte elements)
  char* p = (char*)d_ws;
  float* h      = (float*)p;  p += (size_t)N_NODES * 64 * 4;   // 25.6 MB
  float* agg    = (float*)p;  p += (size_t)N_NODES * 64 * 4;   // 25.6 MB
  int*   csr    = (int*)p;    p += (size_t)N_EDGES * 4;        // 6.4 MB
  int*   rowptr = (int*)p;    p += (size_t)(N_NODES + 1) * 4;
  int*   deg    = (int*)p;    p += (size_t)N_NODES * 4;
  int*   part   = (int*)p;    p += 256 * 4;
  float* agg1   = (float*)p;  p += (size_t)N_NODES * 4;
  float* sub    = (float*)p;  p += (size_t)N_SUB * 64 * 4;
  float* gp     = (float*)p;  p += (size_t)N_GRAPH * 64 * 4;
  if ((size_t)(p - (char*)d_ws) > ws_size) return;  // fail loudly

  // slot (6.4 MB) aliases agg: agg is first written by the gather, which
  // runs after the CSR build completes.
  int* slot = (int*)agg;

  float* outf = (float*)d_out;

  // ---- build CSR (group edges by dst) once; reused by all 4 aggregations
  hipMemsetAsync(deg, 0, N_NODES * sizeof(int), stream);
  count_slot_kernel<<<2048, 256, 0, stream>>>(
      (const int4*)dst, deg, (int4*)slot);
  scan_block_kernel<<<N_SCANB, SCAN_B, 0, stream>>>(deg, rowptr, part);
  scan_partials_kernel<<<1, 128, 0, stream>>>(part);
  add_offsets_kernel<<<N_SCANB, SCAN_B, 0, stream>>>(rowptr, part);
  fill_csr2_kernel<<<2048, 256, 0, stream>>>(
      (const int4*)src, (const int4*)dst, (const int4*)slot, rowptr, csr);

  // ---- conv1
  conv1_agg_kernel<<<1024, 256, 0, stream>>>(x, rowptr, csr, agg1);
  conv1_mlp<<<2048, 256, 0, stream>>>(agg1, c1w1, c1b1, c1w2, c1b2, h);

  // zero pooling buffers before the fused last layer
  hipMemsetAsync(sub, 0, N_SUB * 64 * sizeof(float), stream);
  hipMemsetAsync(gp, 0, N_GRAPH * 64 * sizeof(float), stream);

  // ---- 3 GIN layers: gather + MLP (unfused: each at its own occupancy);
  //      last layer's MLP pools directly into sub (proven free)
  gather64_f4_kernel<<<2048, 256, 0, stream>>>(
      (const float4*)h, rowptr, csr, (float4*)agg);
  gin_mlp<<<2048, 256, 0, stream>>>(agg, cw1 + 0 * 4096, cb1 + 0 * 64,
                                    cw2 + 0 * 4096, cb2 + 0 * 64, h);
  gather64_f4_kernel<<<2048, 256, 0, stream>>>(
      (const float4*)h, rowptr, csr, (float4*)agg);
  gin_mlp<<<2048, 256, 0, stream>>>(agg, cw1 + 1 * 4096, cb1 + 1 * 64,
                                    cw2 + 1 * 4096, cb2 + 1 * 64, h);
  gather64_f4_kernel<<<2048, 256, 0, stream>>>(
      (const float4*)h, rowptr, csr, (float4*)agg);
  gin_mlp_pool<<<2048, 256, 0, stream>>>(agg, cw1 + 2 * 4096, cb1 + 2 * 64,
                                         cw2 + 2 * 4096, cb2 + 2 * 64,
                                         n2s, sub);

  // ---- subgraph -> graph pool + head
  pool_sub<<<64, 256, 0, stream>>>(sub, s2g, gp);
  head_kernel<<<N_GRAPH, 64, 0, stream>>>(gp, l1w, l1b, l2w, l2b, outf);
}